// Round 1
// baseline (1033.395 us; speedup 1.0000x reference)
//
#include <hip/hip_runtime.h>
#include <stdint.h>

// Problem constants
#define TD   512        // model dim D
#define TH   2048       // hidden H
#define TE   8          // experts
#define TT   16384      // tokens = 4*4096

typedef __bf16 bf16x8 __attribute__((ext_vector_type(8)));
typedef float  f32x4  __attribute__((ext_vector_type(4)));

__device__ __forceinline__ void async16(const void* src, void* lds) {
    __builtin_amdgcn_global_load_lds((const __attribute__((address_space(1))) uint32_t*)src,
                                     (__attribute__((address_space(3))) uint32_t*)lds,
                                     16, 0, 0);
}

// ---------------------------------------------------------------------------
// Gate: per-token LayerNorm -> logits(512x8) -> softmax; also cast x -> bf16.
// 1 wave per token, 4 tokens per block.
// ---------------------------------------------------------------------------
__global__ __launch_bounds__(256) void gate_kernel(
    const float* __restrict__ x, const float* __restrict__ gamma,
    const float* __restrict__ beta, const float* __restrict__ gW,
    const float* __restrict__ gb, float* __restrict__ gate_w,
    __bf16* __restrict__ xb)
{
    const int t    = blockIdx.x * 4 + (threadIdx.x >> 6);
    const int lane = threadIdx.x & 63;

    const float* xr = x + (size_t)t * TD + lane * 8;
    float4 v0 = *(const float4*)xr;
    float4 v1 = *(const float4*)(xr + 4);
    float xv[8] = {v0.x, v0.y, v0.z, v0.w, v1.x, v1.y, v1.z, v1.w};

    float s = 0.f, sq = 0.f;
    #pragma unroll
    for (int j = 0; j < 8; ++j) { s += xv[j]; sq += xv[j] * xv[j]; }
    #pragma unroll
    for (int off = 32; off > 0; off >>= 1) {
        s  += __shfl_xor(s, off);
        sq += __shfl_xor(sq, off);
    }
    const float mean = s * (1.f / TD);
    const float var  = sq * (1.f / TD) - mean * mean;
    const float rs   = rsqrtf(var + 1e-5f);

    // cast x to bf16 (raw x, not normalized)
    bf16x8 xc;
    #pragma unroll
    for (int j = 0; j < 8; ++j) xc[j] = (__bf16)xv[j];
    *(bf16x8*)&xb[(size_t)t * TD + lane * 8] = xc;

    // logits partials
    float p[TE] = {};
    #pragma unroll
    for (int j = 0; j < 8; ++j) {
        const int d = lane * 8 + j;
        const float xn = (xv[j] - mean) * rs * gamma[d] + beta[d];
        const float* wr = gW + (size_t)d * TE;
        #pragma unroll
        for (int e = 0; e < TE; ++e) p[e] += xn * wr[e];
    }
    #pragma unroll
    for (int off = 32; off > 0; off >>= 1) {
        #pragma unroll
        for (int e = 0; e < TE; ++e) p[e] += __shfl_xor(p[e], off);
    }

    // softmax (temperature = 1)
    float m = -3.4e38f;
    #pragma unroll
    for (int e = 0; e < TE; ++e) { p[e] += gb[e]; m = fmaxf(m, p[e]); }
    float sum = 0.f;
    #pragma unroll
    for (int e = 0; e < TE; ++e) { p[e] = expf(p[e] - m); sum += p[e]; }
    const float inv = 1.f / sum;
    if (lane == 0) {
        #pragma unroll
        for (int e = 0; e < TE; ++e) gate_w[(size_t)t * TE + e] = p[e] * inv;
    }
}

// ---------------------------------------------------------------------------
// Transpose-cast: src f32 [E][R][C] -> dst bf16 [E][C][R]
// ---------------------------------------------------------------------------
__global__ __launch_bounds__(256) void tcast(
    const float* __restrict__ src, __bf16* __restrict__ dst, int R, int C)
{
    __shared__ __bf16 tile[64][65];
    const int e  = blockIdx.z;
    const int r0 = blockIdx.y * 64, c0 = blockIdx.x * 64;
    const int tr = threadIdx.x >> 6;   // 0..3
    const int tc = threadIdx.x & 63;

    const float* s = src + ((size_t)e * R + r0) * C + c0;
    #pragma unroll
    for (int i = 0; i < 16; ++i) {
        const int r = i * 4 + tr;
        tile[r][tc] = (__bf16)s[(size_t)r * C + tc];
    }
    __syncthreads();
    __bf16* d = dst + ((size_t)e * C + c0) * R + r0;
    #pragma unroll
    for (int i = 0; i < 16; ++i) {
        const int c = i * 4 + tr;
        d[(size_t)c * R + tc] = tile[tc][c];
    }
}

// ---------------------------------------------------------------------------
// bf16 MFMA GEMM, 128x128 tile, BK=32, 4 waves, single-buffered 2-barrier loop.
// A: [M][K] row-major bf16.  Bt: [N][K] row-major bf16 (B transposed).
// EPI 0: C = leaky(A*B + bias) -> bf16 [M][N]
// EPI 1: out = gw[r][e] * (A*B + bias)       (f32 store)
// EPI 2: out += gw[r][e] * (A*B + bias)      (f32 rmw)
// ---------------------------------------------------------------------------
template <int EPI>
__global__ __launch_bounds__(256) void moe_gemm(
    const __bf16* __restrict__ A, const __bf16* __restrict__ Bt,
    const float* __restrict__ bias, void* __restrict__ Cout,
    const float* __restrict__ gw, int M, int N, int K, int e)
{
    __shared__ __bf16 As[128 * 32];
    __shared__ __bf16 Bs[128 * 32];

    const int tid  = threadIdx.x;
    const int w    = tid >> 6;
    const int lane = tid & 63;
    const int nbn  = N >> 7;
    const int bm   = blockIdx.x / nbn, bn = blockIdx.x % nbn;
    const int wr   = w >> 1, wc = w & 1;

    f32x4 acc[4][4] = {};

    // staging: wave w loads A rows [w*32, w*32+32) and B rows likewise
    const int srow  = lane >> 2;     // 0..15 within a 16-row chunk
    const int sslot = lane & 3;      // 16B slot within the 64B row (8 bf16)
    const size_t arow0 = (size_t)bm * 128 + w * 32 + srow;
    const size_t brow0 = (size_t)bn * 128 + w * 32 + srow;
    const __bf16* aBase = A  + arow0 * K + sslot * 8;
    const __bf16* bBase = Bt + brow0 * K + sslot * 8;

    const int fr = lane & 15;        // fragment row/col
    const int ks = lane >> 4;        // k-slot 0..3

    for (int kt = 0; kt < (K >> 5); ++kt) {
        __syncthreads();
        const __bf16* ga = aBase + kt * 32;
        const __bf16* gb = bBase + kt * 32;
        async16(ga,          &As[(2 * w + 0) * 512]);
        async16(ga + 16 * K, &As[(2 * w + 1) * 512]);
        async16(gb,          &Bs[(2 * w + 0) * 512]);
        async16(gb + 16 * K, &Bs[(2 * w + 1) * 512]);
        __syncthreads();

        bf16x8 af[4], bf[4];
        #pragma unroll
        for (int m = 0; m < 4; ++m)
            af[m] = *(const bf16x8*)&As[(wr * 64 + m * 16 + fr) * 32 + ks * 8];
        #pragma unroll
        for (int n = 0; n < 4; ++n)
            bf[n] = *(const bf16x8*)&Bs[(wc * 64 + n * 16 + fr) * 32 + ks * 8];
        #pragma unroll
        for (int m = 0; m < 4; ++m)
            #pragma unroll
            for (int n = 0; n < 4; ++n)
                acc[m][n] = __builtin_amdgcn_mfma_f32_16x16x32_bf16(af[m], bf[n], acc[m][n], 0, 0, 0);
    }

    // epilogue — C/D map: col = lane&15, row = (lane>>4)*4 + j   [m89-verified]
    const int rj = (lane >> 4) * 4;
    #pragma unroll
    for (int m = 0; m < 4; ++m) {
        const int grb = bm * 128 + wr * 64 + m * 16 + rj;
        #pragma unroll
        for (int n = 0; n < 4; ++n) {
            const int gc = bn * 128 + wc * 64 + n * 16 + fr;
            const float bval = bias[gc];
            #pragma unroll
            for (int j = 0; j < 4; ++j) {
                const int gr = grb + j;
                float v = acc[m][n][j] + bval;
                if (EPI == 0) {
                    v = v > 0.f ? v : 0.01f * v;
                    ((__bf16*)Cout)[(size_t)gr * N + gc] = (__bf16)v;
                } else {
                    const float wgt = gw[(size_t)gr * TE + e];
                    float* op = (float*)Cout + (size_t)gr * N + gc;
                    if (EPI == 1) *op = wgt * v;
                    else          *op += wgt * v;
                }
            }
        }
    }
}

// ---------------------------------------------------------------------------
extern "C" void kernel_launch(void* const* d_in, const int* in_sizes, int n_in,
                              void* d_out, int out_size, void* d_ws, size_t ws_size,
                              hipStream_t stream)
{
    const float* x     = (const float*)d_in[0];
    const float* gamma = (const float*)d_in[1];
    const float* beta  = (const float*)d_in[2];
    const float* gW    = (const float*)d_in[3];
    const float* gb    = (const float*)d_in[4];
    const float* W1    = (const float*)d_in[5];
    const float* b1    = (const float*)d_in[6];
    const float* W2    = (const float*)d_in[7];
    const float* b2    = (const float*)d_in[8];

    char* ws = (char*)d_ws;
    size_t off = 0;
    float*  gate_w = (float*)(ws + off);  off += (size_t)TT * TE * 4;        // 512 KB
    __bf16* xb     = (__bf16*)(ws + off); off += (size_t)TT * TD * 2;        // 16 MB
    __bf16* W1t    = (__bf16*)(ws + off); off += (size_t)TE * TD * TH * 2;   // 16 MB
    __bf16* W2t    = (__bf16*)(ws + off); off += (size_t)TE * TD * TH * 2;   // 16 MB
    __bf16* hb     = (__bf16*)(ws + off);                                    // 64 MB (one expert)

    gate_kernel<<<TT / 4, 256, 0, stream>>>(x, gamma, beta, gW, gb, gate_w, xb);
    // W1 [E][D][H] -> W1t [E][H][D];  W2 [E][H][D] -> W2t [E][D][H]
    tcast<<<dim3(TH / 64, TD / 64, TE), 256, 0, stream>>>(W1, W1t, TD, TH);
    tcast<<<dim3(TD / 64, TH / 64, TE), 256, 0, stream>>>(W2, W2t, TH, TD);

    const int g1 = (TT / 128) * (TH / 128);   // 2048 blocks
    const int g2 = (TT / 128) * (TD / 128);   // 512 blocks
    for (int e = 0; e < TE; ++e) {
        moe_gemm<0><<<g1, 256, 0, stream>>>(xb, W1t + (size_t)e * TH * TD,
                                            b1 + (size_t)e * TH, (void*)hb,
                                            nullptr, TT, TH, TD, e);
        if (e == 0)
            moe_gemm<1><<<g2, 256, 0, stream>>>(hb, W2t + (size_t)e * TD * TH,
                                                b2 + (size_t)e * TD, d_out,
                                                gate_w, TT, TD, TH, e);
        else
            moe_gemm<2><<<g2, 256, 0, stream>>>(hb, W2t + (size_t)e * TD * TH,
                                                b2 + (size_t)e * TD, d_out,
                                                gate_w, TT, TD, TH, e);
    }
}

// Round 2
// 883.101 us; speedup vs baseline: 1.1702x; 1.1702x over previous
//
#include <hip/hip_runtime.h>
#include <stdint.h>

#define TD 512
#define TH 2048
#define TE 8
#define TT 16384

typedef __bf16 bf16x8 __attribute__((ext_vector_type(8)));
typedef float  f32x4  __attribute__((ext_vector_type(4)));

__device__ __forceinline__ void async16(const void* src, void* lds) {
    __builtin_amdgcn_global_load_lds((const __attribute__((address_space(1))) uint32_t*)src,
                                     (__attribute__((address_space(3))) uint32_t*)lds,
                                     16, 0, 0);
}

// ---------------------------------------------------------------------------
// Gate: per-token LayerNorm -> logits -> softmax -> gate_w; cast x->bf16;
// write out_bias[t][d] = sum_e gw[t][e]*b2[e][d] directly into d_out.
// ---------------------------------------------------------------------------
__global__ __launch_bounds__(256) void gate_kernel(
    const float* __restrict__ x, const float* __restrict__ gamma,
    const float* __restrict__ beta, const float* __restrict__ gW,
    const float* __restrict__ gb, const float* __restrict__ b2,
    float* __restrict__ gate_w, __bf16* __restrict__ xb,
    float* __restrict__ outp)
{
    const int t    = blockIdx.x * 4 + (threadIdx.x >> 6);
    const int lane = threadIdx.x & 63;

    const float* xr = x + (size_t)t * TD + lane * 8;
    float4 v0 = *(const float4*)xr;
    float4 v1 = *(const float4*)(xr + 4);
    float xv[8] = {v0.x, v0.y, v0.z, v0.w, v1.x, v1.y, v1.z, v1.w};

    float s = 0.f, sq = 0.f;
    #pragma unroll
    for (int j = 0; j < 8; ++j) { s += xv[j]; sq += xv[j] * xv[j]; }
    #pragma unroll
    for (int off = 32; off > 0; off >>= 1) {
        s  += __shfl_xor(s, off);
        sq += __shfl_xor(sq, off);
    }
    const float mean = s * (1.f / TD);
    const float var  = sq * (1.f / TD) - mean * mean;
    const float rs   = rsqrtf(var + 1e-5f);

    bf16x8 xc;
    #pragma unroll
    for (int j = 0; j < 8; ++j) xc[j] = (__bf16)xv[j];
    *(bf16x8*)&xb[(size_t)t * TD + lane * 8] = xc;

    float p[TE] = {};
    #pragma unroll
    for (int j = 0; j < 8; ++j) {
        const int d = lane * 8 + j;
        const float xn = (xv[j] - mean) * rs * gamma[d] + beta[d];
        const float* wr = gW + (size_t)d * TE;
        #pragma unroll
        for (int e = 0; e < TE; ++e) p[e] += xn * wr[e];
    }
    #pragma unroll
    for (int off = 32; off > 0; off >>= 1) {
        #pragma unroll
        for (int e = 0; e < TE; ++e) p[e] += __shfl_xor(p[e], off);
    }

    float m = -3.4e38f;
    #pragma unroll
    for (int e = 0; e < TE; ++e) { p[e] += gb[e]; m = fmaxf(m, p[e]); }
    float sum = 0.f;
    #pragma unroll
    for (int e = 0; e < TE; ++e) { p[e] = expf(p[e] - m); sum += p[e]; }
    const float inv = 1.f / sum;
    if (lane == 0) {
        #pragma unroll
        for (int e = 0; e < TE; ++e) gate_w[(size_t)t * TE + e] = p[e] * inv;
    }

    // out bias term: sum_e gw*b2[e][d]  (all lanes have full p[] via butterfly)
    float ob[8] = {};
    #pragma unroll
    for (int e = 0; e < TE; ++e) {
        const float we = p[e] * inv;
        const float* b2r = b2 + (size_t)e * TD + lane * 8;
        #pragma unroll
        for (int j = 0; j < 8; ++j) ob[j] += we * b2r[j];
    }
    float4 o0 = {ob[0], ob[1], ob[2], ob[3]};
    float4 o1 = {ob[4], ob[5], ob[6], ob[7]};
    *(float4*)&outp[(size_t)t * TD + lane * 8]     = o0;
    *(float4*)&outp[(size_t)t * TD + lane * 8 + 4] = o1;
}

// ---------------------------------------------------------------------------
// Transpose-cast: src f32 [E][R][C] -> dst bf16 [E][C][R]
// ---------------------------------------------------------------------------
__global__ __launch_bounds__(256) void tcast(
    const float* __restrict__ src, __bf16* __restrict__ dst, int R, int C)
{
    __shared__ __bf16 tile[64][65];
    const int e  = blockIdx.z;
    const int r0 = blockIdx.y * 64, c0 = blockIdx.x * 64;
    const int tr = threadIdx.x >> 6;
    const int tc = threadIdx.x & 63;

    const float* s = src + ((size_t)e * R + r0) * C + c0;
    #pragma unroll
    for (int i = 0; i < 16; ++i) {
        const int r = i * 4 + tr;
        tile[r][tc] = (__bf16)s[(size_t)r * C + tc];
    }
    __syncthreads();
    __bf16* d = dst + ((size_t)e * C + c0) * R + r0;
    #pragma unroll
    for (int i = 0; i < 16; ++i) {
        const int c = i * 4 + tr;
        d[(size_t)c * R + tc] = tile[tc][c];
    }
}

// ---------------------------------------------------------------------------
// 8-phase 256x256 bf16 MFMA GEMM, BK=64, 8 waves (2M x 4N), 128 KiB LDS.
// A: [M][K] row-major bf16.  Bt: [N][K] row-major bf16.
// LDS: A/B x dbuf x kstep, each region [256 rows][32 k] bf16 = 16 KiB,
// XOR-swizzled 16B chunks: chunk c' = c ^ ((row>>1)&3)  (both-sides, rule 21).
// Stage order: half h = 4*tile + {A-k0,B-k0,A-k1,B-k1} staged at phase h-6.
// vmcnt(8) at odd phases (after stage) => halves needed 2 phases later landed
// before the separating barrier; region overwrite always after last-read phase.
// EPI 0: h' = bf16( gw[m][e] * leaky(acc + b1[col]) )  -> [M][TH]
// EPI 1: atomicAdd(out[m][col], acc)   (2 experts per launch, e from blockIdx)
// ---------------------------------------------------------------------------
template <int EPI>
__global__ __launch_bounds__(512, 2) void gemm8p(
    const __bf16* __restrict__ A, const __bf16* __restrict__ Bt,
    const float* __restrict__ bias, const float* __restrict__ gw,
    void* __restrict__ C, int K, int e)
{
    __shared__ __align__(16) char smem[131072];
    const int tid  = threadIdx.x;
    const int w    = tid >> 6, lane = tid & 63;
    const int wr   = w >> 2, wc = w & 3;      // 2 x 4 wave grid
    const int fr   = lane & 15, ks = lane >> 4;

    int bm, bn;
    if (EPI == 0) {
        bn = blockIdx.x & 7;          // 8 bn panels, one per XCD
        bm = blockIdx.x >> 3;         // 64
    } else {
        const int xcd = blockIdx.x & 7, idx = blockIdx.x >> 3; // 256 blocks
        bn = xcd >> 2;                               // 2 bn panels
        const int sub  = xcd & 3;
        const int eloc = idx >> 4;                   // 2 experts in-launch
        bm = sub * 16 + (idx & 15);                  // 64
        A  += (size_t)eloc * TT * TH;
        Bt += (size_t)eloc * TD * TH;
        e = eloc;
    }

    const __bf16* Ab = A  + (size_t)bm * 256 * K;
    const __bf16* Bb = Bt + (size_t)bn * 256 * K;
    const int NT = K >> 6;

    f32x4 acc[8][4] = {};

    auto stage = [&](int h) {
        const int th = h >> 2, j = h & 3;
        const int mat = j & 1, hks = j >> 1, hbuf = th & 1;
        const __bf16* mb = mat ? Bb : Ab;
        char* region = smem + mat * 65536 + hbuf * 32768 + hks * 16384;
        #pragma unroll
        for (int i = 0; i < 2; ++i) {
            const int cid = i * 512 + tid;
            const int row = cid >> 2;
            const int gc  = (cid & 3) ^ ((row >> 1) & 3);   // inverse swizzle on source
            async16(mb + (size_t)row * K + th * 64 + hks * 32 + gc * 8,
                    region + i * 8192 + w * 1024);
        }
    };

    // prologue: halves 0..5 (tile0 full + tile1 k0)
    #pragma unroll
    for (int h = 0; h < 6; ++h) stage(h);
    asm volatile("s_waitcnt vmcnt(8)" ::: "memory");   // halves 0,1 landed
    __builtin_amdgcn_sched_barrier(0);
    __builtin_amdgcn_s_barrier();

    bf16x8 areg[8];

    for (int t = 0; t < NT; ++t) {
        const int buf = t & 1;
        const char* aB = smem + buf * 32768;
        const char* bB = smem + 65536 + buf * 32768;
        #pragma unroll
        for (int q = 0; q < 4; ++q) {
            const int kst = q >> 1, nh = q & 1;
            const char* aR = aB + kst * 16384;
            const char* bR = bB + kst * 16384;
            if (nh == 0) {
                #pragma unroll
                for (int m = 0; m < 8; ++m) {
                    const int row = wr * 128 + m * 16 + fr;
                    areg[m] = *(const bf16x8*)(aR + row * 64 + (((ks ^ (row >> 1)) & 3) << 4));
                }
            }
            bf16x8 bf0, bf1;
            {
                const int r0 = wc * 64 + nh * 32 + fr;
                const int r1 = r0 + 16;
                bf0 = *(const bf16x8*)(bR + r0 * 64 + (((ks ^ (r0 >> 1)) & 3) << 4));
                bf1 = *(const bf16x8*)(bR + r1 * 64 + (((ks ^ (r1 >> 1)) & 3) << 4));
            }
            const int h = t * 4 + q + 6;
            if (h < NT * 4) stage(h);
            if (nh == 1) { asm volatile("s_waitcnt vmcnt(8)" ::: "memory"); }
            __builtin_amdgcn_sched_barrier(0);
            __builtin_amdgcn_s_barrier();
            asm volatile("s_waitcnt lgkmcnt(0)" ::: "memory");
            __builtin_amdgcn_sched_barrier(0);
            __builtin_amdgcn_s_setprio(1);
            #pragma unroll
            for (int m = 0; m < 8; ++m) {
                acc[m][nh*2+0] = __builtin_amdgcn_mfma_f32_16x16x32_bf16(areg[m], bf0, acc[m][nh*2+0], 0, 0, 0);
                acc[m][nh*2+1] = __builtin_amdgcn_mfma_f32_16x16x32_bf16(areg[m], bf1, acc[m][nh*2+1], 0, 0, 0);
            }
            __builtin_amdgcn_s_setprio(0);
            __builtin_amdgcn_sched_barrier(0);
            __builtin_amdgcn_s_barrier();
        }
    }

    // epilogue — C/D map: col = lane&15, row = (lane>>4)*4 + j
    const int rj = (lane >> 4) << 2;
    if (EPI == 0) {
        __bf16* hC = (__bf16*)C;
        #pragma unroll
        for (int m = 0; m < 8; ++m) {
            const int gr0 = bm * 256 + wr * 128 + m * 16 + rj;
            #pragma unroll
            for (int j = 0; j < 4; ++j) {
                const int gr = gr0 + j;
                const float wgt = gw[(size_t)gr * TE + e];
                #pragma unroll
                for (int n = 0; n < 4; ++n) {
                    const int gc = bn * 256 + wc * 64 + n * 16 + fr;
                    float v = acc[m][n][j] + bias[gc];
                    v = v > 0.f ? v : 0.01f * v;
                    hC[(size_t)gr * TH + gc] = (__bf16)(v * wgt);
                }
            }
        }
    } else {
        float* oC = (float*)C;
        #pragma unroll
        for (int m = 0; m < 8; ++m) {
            const int gr0 = bm * 256 + wr * 128 + m * 16 + rj;
            #pragma unroll
            for (int j = 0; j < 4; ++j) {
                const int gr = gr0 + j;
                #pragma unroll
                for (int n = 0; n < 4; ++n) {
                    const int gc = bn * 256 + wc * 64 + n * 16 + fr;
                    atomicAdd(oC + (size_t)gr * TD + gc, acc[m][n][j]);
                }
            }
        }
    }
}

// ---------------------------------------------------------------------------
extern "C" void kernel_launch(void* const* d_in, const int* in_sizes, int n_in,
                              void* d_out, int out_size, void* d_ws, size_t ws_size,
                              hipStream_t stream)
{
    const float* x     = (const float*)d_in[0];
    const float* gamma = (const float*)d_in[1];
    const float* beta  = (const float*)d_in[2];
    const float* gW    = (const float*)d_in[3];
    const float* gb    = (const float*)d_in[4];
    const float* W1    = (const float*)d_in[5];
    const float* b1    = (const float*)d_in[6];
    const float* W2    = (const float*)d_in[7];
    const float* b2    = (const float*)d_in[8];

    char* ws = (char*)d_ws;
    size_t off = 0;
    float*  gate_w = (float*)(ws + off);  off += (size_t)TT * TE * 4;        // 0.5 MB
    __bf16* xb     = (__bf16*)(ws + off); off += (size_t)TT * TD * 2;        // 16 MB
    __bf16* W1t    = (__bf16*)(ws + off); off += (size_t)TE * TD * TH * 2;   // 16 MB
    __bf16* W2t    = (__bf16*)(ws + off); off += (size_t)TE * TD * TH * 2;   // 16 MB
    __bf16* hg     = (__bf16*)(ws + off);                                    // 128 MB (2 experts)

    gate_kernel<<<TT / 4, 256, 0, stream>>>(x, gamma, beta, gW, gb, b2,
                                            gate_w, xb, (float*)d_out);
    // W1 [E][D][H] -> W1t [E][H][D];  W2 [E][H][D] -> W2t [E][D][H]
    tcast<<<dim3(TH / 64, TD / 64, TE), 256, 0, stream>>>(W1, W1t, TD, TH);
    tcast<<<dim3(TD / 64, TH / 64, TE), 256, 0, stream>>>(W2, W2t, TH, TD);

    for (int g = 0; g < 4; ++g) {
        #pragma unroll
        for (int s = 0; s < 2; ++s) {
            const int e = 2 * g + s;
            gemm8p<0><<<512, 512, 0, stream>>>(
                xb, W1t + (size_t)e * TH * TD, b1 + (size_t)e * TH, gate_w,
                (void*)(hg + (size_t)s * TT * TH), TD /*K=512*/, e);
        }
        gemm8p<1><<<256, 512, 0, stream>>>(
            hg, W2t + (size_t)(2 * g) * TD * TH, nullptr, nullptr,
            d_out, TH /*K=2048*/, 0);
    }
}

// Round 3
// 858.350 us; speedup vs baseline: 1.2039x; 1.0288x over previous
//
#include <hip/hip_runtime.h>
#include <stdint.h>

#define TD 512
#define TH 2048
#define TE 8
#define TT 16384

typedef __bf16 bf16x8 __attribute__((ext_vector_type(8)));
typedef __bf16 bf16x4 __attribute__((ext_vector_type(4)));
typedef float  f32x4  __attribute__((ext_vector_type(4)));

__device__ __forceinline__ void async16(const void* src, void* lds) {
    __builtin_amdgcn_global_load_lds((const __attribute__((address_space(1))) uint32_t*)src,
                                     (__attribute__((address_space(3))) uint32_t*)lds,
                                     16, 0, 0);
}

// ---------------------------------------------------------------------------
// Gate: per-token LayerNorm -> logits -> softmax -> gate_w; cast x->bf16;
// write out_bias[t][d] = sum_e gw[t][e]*b2[e][d] directly into d_out.
// ---------------------------------------------------------------------------
__global__ __launch_bounds__(256) void gate_kernel(
    const float* __restrict__ x, const float* __restrict__ gamma,
    const float* __restrict__ beta, const float* __restrict__ gW,
    const float* __restrict__ gb, const float* __restrict__ b2,
    float* __restrict__ gate_w, __bf16* __restrict__ xb,
    float* __restrict__ outp)
{
    const int t    = blockIdx.x * 4 + (threadIdx.x >> 6);
    const int lane = threadIdx.x & 63;

    const float* xr = x + (size_t)t * TD + lane * 8;
    float4 v0 = *(const float4*)xr;
    float4 v1 = *(const float4*)(xr + 4);
    float xv[8] = {v0.x, v0.y, v0.z, v0.w, v1.x, v1.y, v1.z, v1.w};

    float s = 0.f, sq = 0.f;
    #pragma unroll
    for (int j = 0; j < 8; ++j) { s += xv[j]; sq += xv[j] * xv[j]; }
    #pragma unroll
    for (int off = 32; off > 0; off >>= 1) {
        s  += __shfl_xor(s, off);
        sq += __shfl_xor(sq, off);
    }
    const float mean = s * (1.f / TD);
    const float var  = sq * (1.f / TD) - mean * mean;
    const float rs   = rsqrtf(var + 1e-5f);

    bf16x8 xc;
    #pragma unroll
    for (int j = 0; j < 8; ++j) xc[j] = (__bf16)xv[j];
    *(bf16x8*)&xb[(size_t)t * TD + lane * 8] = xc;

    float p[TE] = {};
    #pragma unroll
    for (int j = 0; j < 8; ++j) {
        const int d = lane * 8 + j;
        const float xn = (xv[j] - mean) * rs * gamma[d] + beta[d];
        const float* wr = gW + (size_t)d * TE;
        #pragma unroll
        for (int e = 0; e < TE; ++e) p[e] += xn * wr[e];
    }
    #pragma unroll
    for (int off = 32; off > 0; off >>= 1) {
        #pragma unroll
        for (int e = 0; e < TE; ++e) p[e] += __shfl_xor(p[e], off);
    }

    float m = -3.4e38f;
    #pragma unroll
    for (int e = 0; e < TE; ++e) { p[e] += gb[e]; m = fmaxf(m, p[e]); }
    float sum = 0.f;
    #pragma unroll
    for (int e = 0; e < TE; ++e) { p[e] = expf(p[e] - m); sum += p[e]; }
    const float inv = 1.f / sum;
    if (lane == 0) {
        #pragma unroll
        for (int e = 0; e < TE; ++e) gate_w[(size_t)t * TE + e] = p[e] * inv;
    }

    float ob[8] = {};
    #pragma unroll
    for (int e = 0; e < TE; ++e) {
        const float we = p[e] * inv;
        const float* b2r = b2 + (size_t)e * TD + lane * 8;
        #pragma unroll
        for (int j = 0; j < 8; ++j) ob[j] += we * b2r[j];
    }
    float4 o0 = {ob[0], ob[1], ob[2], ob[3]};
    float4 o1 = {ob[4], ob[5], ob[6], ob[7]};
    *(float4*)&outp[(size_t)t * TD + lane * 8]     = o0;
    *(float4*)&outp[(size_t)t * TD + lane * 8 + 4] = o1;
}

// ---------------------------------------------------------------------------
// Transpose-cast.  src f32 [E][R][C].
// MODE 0 (W1): dst[e][c][r]                      (row stride R)
// MODE 1 (W2): dst[e>>1][c][(e&1)*R + r]         (row stride 2R = 4096)
// ---------------------------------------------------------------------------
template <int MODE>
__global__ __launch_bounds__(256) void tcast(
    const float* __restrict__ src, __bf16* __restrict__ dst, int R, int C)
{
    __shared__ __bf16 tile[64][65];
    const int e  = blockIdx.z;
    const int r0 = blockIdx.y * 64, c0 = blockIdx.x * 64;
    const int tr = threadIdx.x >> 6;
    const int tc = threadIdx.x & 63;

    const float* s = src + ((size_t)e * R + r0) * C + c0;
    #pragma unroll
    for (int i = 0; i < 16; ++i) {
        const int r = i * 4 + tr;
        tile[r][tc] = (__bf16)s[(size_t)r * C + tc];
    }
    __syncthreads();

    size_t RS, eoff;
    if (MODE == 0) { RS = (size_t)R;     eoff = (size_t)e * C * R; }
    else           { RS = (size_t)2 * R; eoff = (size_t)(e >> 1) * C * 2 * R + (size_t)(e & 1) * R; }

    __bf16* d = dst + eoff + (size_t)c0 * RS + r0;
    #pragma unroll
    for (int i = 0; i < 16; ++i) {
        const int c = i * 4 + tr;
        d[(size_t)c * RS + tc] = tile[tc][c];
    }
}

// ---------------------------------------------------------------------------
// 8-phase 256x256 bf16 MFMA GEMM, BK=64, 8 waves (2M x 4N), 128 KiB LDS.
// Hot loop identical to the round-2 verified skeleton (vmcnt(8) at odd
// phases, lgkmcnt(0)+sched_barrier before MFMA cluster, setprio around it,
// both-sides XOR swizzle on 16B chunks).
//
// EPI 0 (GEMM1): A=xb [T][512], Bt=W1t panels, K=512, S=512, NT=8.
//   2 experts per launch (1024 blocks). XCD-chunked: xcd owns 8 bm tiles
//   (2 MB xb chunk L2-resident) x {e2 x bn}.
//   MFMA operands SWAPPED -> lane&15 = M-row, reg j = N-col. Epilogue packs
//   4 cols -> one 8B bf16x4 store into h[t][e2*TH + col] (row stride 2*TH).
// EPI 1 (GEMM2): A=h [T][4096], Bt=W2tc [512][4096] panels, K=2048 (k-half
//   split), S=4096, NT=32. atomicAdd f32 into d_out; both k-halves of a
//   (bm,bn) tile live on the same XCD (atomics localize to one L2).
// ---------------------------------------------------------------------------
template <int EPI>
__global__ __launch_bounds__(512, 2) void gemm8p(
    const __bf16* __restrict__ A, const __bf16* __restrict__ Bt,
    const float* __restrict__ b1, const float* __restrict__ gw,
    void* __restrict__ C, int grp)
{
    constexpr int K = (EPI == 0) ? TD : TH;        // 512 / 2048
    constexpr int S = (EPI == 0) ? TD : 2 * TH;    // row stride 512 / 4096
    constexpr int NT = K >> 6;

    __shared__ __align__(16) char smem[131072];
    const int tid  = threadIdx.x;
    const int w    = tid >> 6, lane = tid & 63;
    const int wr   = w >> 2, wc = w & 3;
    const int fr   = lane & 15, ks = lane >> 4;

    int bm, bn, e2 = 0, e = 0;
    if (EPI == 0) {
        const int xcd = blockIdx.x & 7, idx = blockIdx.x >> 3;  // 8 x 128
        bm = xcd * 8 + (idx & 7);
        e2 = (idx >> 3) & 1;
        bn = idx >> 4;                                          // 0..7
        e  = grp * 2 + e2;
        A  += (size_t)bm * 256 * S;
        Bt += (size_t)e2 * TH * TD + (size_t)bn * 256 * S;
        b1 += (size_t)e * TH;
    } else {
        const int xcd = blockIdx.x & 7, idx = blockIdx.x >> 3;  // 8 x 32
        bn = xcd & 1;
        bm = (xcd >> 1) * 16 + (idx & 15);
        const int kh = idx >> 4;                                // k-half
        A  += (size_t)bm * 256 * S + (size_t)kh * 2048;
        Bt += (size_t)bn * 256 * S + (size_t)kh * 2048;
    }

    const __bf16* Ab = A;
    const __bf16* Bb = Bt;

    f32x4 acc[8][4] = {};

    auto stage = [&](int h) {
        const int th = h >> 2, j = h & 3;
        const int mat = j & 1, hks = j >> 1, hbuf = th & 1;
        const __bf16* mb = mat ? Bb : Ab;
        char* region = smem + mat * 65536 + hbuf * 32768 + hks * 16384;
        #pragma unroll
        for (int i = 0; i < 2; ++i) {
            const int cid = i * 512 + tid;
            const int row = cid >> 2;
            const int gc  = (cid & 3) ^ ((row >> 1) & 3);
            async16(mb + (size_t)row * S + th * 64 + hks * 32 + gc * 8,
                    region + i * 8192 + w * 1024);
        }
    };

    #pragma unroll
    for (int h = 0; h < 6; ++h) stage(h);
    asm volatile("s_waitcnt vmcnt(8)" ::: "memory");
    __builtin_amdgcn_sched_barrier(0);
    __builtin_amdgcn_s_barrier();

    bf16x8 areg[8];

    for (int t = 0; t < NT; ++t) {
        const int buf = t & 1;
        const char* aB = smem + buf * 32768;
        const char* bB = smem + 65536 + buf * 32768;
        #pragma unroll
        for (int q = 0; q < 4; ++q) {
            const int kst = q >> 1, nh = q & 1;
            const char* aR = aB + kst * 16384;
            const char* bR = bB + kst * 16384;
            if (nh == 0) {
                #pragma unroll
                for (int m = 0; m < 8; ++m) {
                    const int row = wr * 128 + m * 16 + fr;
                    areg[m] = *(const bf16x8*)(aR + row * 64 + (((ks ^ (row >> 1)) & 3) << 4));
                }
            }
            bf16x8 bf0, bf1;
            {
                const int r0 = wc * 64 + nh * 32 + fr;
                const int r1 = r0 + 16;
                bf0 = *(const bf16x8*)(bR + r0 * 64 + (((ks ^ (r0 >> 1)) & 3) << 4));
                bf1 = *(const bf16x8*)(bR + r1 * 64 + (((ks ^ (r1 >> 1)) & 3) << 4));
            }
            const int h = t * 4 + q + 6;
            if (h < NT * 4) stage(h);
            if (nh == 1) { asm volatile("s_waitcnt vmcnt(8)" ::: "memory"); }
            __builtin_amdgcn_sched_barrier(0);
            __builtin_amdgcn_s_barrier();
            asm volatile("s_waitcnt lgkmcnt(0)" ::: "memory");
            __builtin_amdgcn_sched_barrier(0);
            __builtin_amdgcn_s_setprio(1);
            #pragma unroll
            for (int m = 0; m < 8; ++m) {
                if (EPI == 0) {   // swapped: lane&15 -> M-row, reg j -> N-col
                    acc[m][nh*2+0] = __builtin_amdgcn_mfma_f32_16x16x32_bf16(bf0, areg[m], acc[m][nh*2+0], 0, 0, 0);
                    acc[m][nh*2+1] = __builtin_amdgcn_mfma_f32_16x16x32_bf16(bf1, areg[m], acc[m][nh*2+1], 0, 0, 0);
                } else {
                    acc[m][nh*2+0] = __builtin_amdgcn_mfma_f32_16x16x32_bf16(areg[m], bf0, acc[m][nh*2+0], 0, 0, 0);
                    acc[m][nh*2+1] = __builtin_amdgcn_mfma_f32_16x16x32_bf16(areg[m], bf1, acc[m][nh*2+1], 0, 0, 0);
                }
            }
            __builtin_amdgcn_s_setprio(0);
            __builtin_amdgcn_sched_barrier(0);
            __builtin_amdgcn_s_barrier();
        }
    }

    if (EPI == 0) {
        // lane&15 = row, (lane>>4)*4 + j = col
        __bf16* hC = (__bf16*)C;
        const int rjc = (lane >> 4) << 2;
        #pragma unroll
        for (int m = 0; m < 8; ++m) {
            const int row = bm * 256 + wr * 128 + m * 16 + fr;
            const float wgt = gw[(size_t)row * TE + e];
            __bf16* hrow = hC + (size_t)row * (2 * TH) + e2 * TH;
            #pragma unroll
            for (int n = 0; n < 4; ++n) {
                const int colb = bn * 256 + wc * 64 + n * 16 + rjc;
                const f32x4 bv = *(const f32x4*)&b1[colb];
                bf16x4 ov;
                #pragma unroll
                for (int j = 0; j < 4; ++j) {
                    float v = acc[m][n][j] + bv[j];
                    v = v > 0.f ? v : 0.01f * v;
                    ov[j] = (__bf16)(v * wgt);
                }
                *(bf16x4*)&hrow[colb] = ov;
            }
        }
    } else {
        // col = lane&15, row = (lane>>4)*4 + j
        float* oC = (float*)C;
        const int rj = (lane >> 4) << 2;
        #pragma unroll
        for (int m = 0; m < 8; ++m) {
            const int gr0 = bm * 256 + wr * 128 + m * 16 + rj;
            #pragma unroll
            for (int j = 0; j < 4; ++j) {
                const int gr = gr0 + j;
                #pragma unroll
                for (int n = 0; n < 4; ++n) {
                    const int gc = bn * 256 + wc * 64 + n * 16 + fr;
                    atomicAdd(oC + (size_t)gr * TD + gc, acc[m][n][j]);
                }
            }
        }
    }
}

// ---------------------------------------------------------------------------
extern "C" void kernel_launch(void* const* d_in, const int* in_sizes, int n_in,
                              void* d_out, int out_size, void* d_ws, size_t ws_size,
                              hipStream_t stream)
{
    const float* x     = (const float*)d_in[0];
    const float* gamma = (const float*)d_in[1];
    const float* beta  = (const float*)d_in[2];
    const float* gW    = (const float*)d_in[3];
    const float* gb    = (const float*)d_in[4];
    const float* W1    = (const float*)d_in[5];
    const float* b1    = (const float*)d_in[6];
    const float* W2    = (const float*)d_in[7];
    const float* b2    = (const float*)d_in[8];

    char* ws = (char*)d_ws;
    size_t off = 0;
    float*  gate_w = (float*)(ws + off);  off += (size_t)TT * TE * 4;        // 0.5 MB
    __bf16* xb     = (__bf16*)(ws + off); off += (size_t)TT * TD * 2;        // 16 MB
    __bf16* W1t    = (__bf16*)(ws + off); off += (size_t)TE * TD * TH * 2;   // 16 MB
    __bf16* W2tc   = (__bf16*)(ws + off); off += (size_t)TE * TD * TH * 2;   // 16 MB
    __bf16* h      = (__bf16*)(ws + off);                                    // 128 MB

    gate_kernel<<<TT / 4, 256, 0, stream>>>(x, gamma, beta, gW, gb, b2,
                                            gate_w, xb, (float*)d_out);
    // W1 [E][D][H] -> W1t [E][H][D]
    tcast<0><<<dim3(TH / 64, TD / 64, TE), 256, 0, stream>>>(W1, W1t, TD, TH);
    // W2 [E][H][D] -> W2tc [E/2][D][2*TH] (pair-concat along K)
    tcast<1><<<dim3(TD / 64, TH / 64, TE), 256, 0, stream>>>(W2, W2tc, TH, TD);

    for (int grp = 0; grp < 4; ++grp) {
        gemm8p<0><<<1024, 512, 0, stream>>>(
            xb, W1t + (size_t)grp * 2 * TH * TD, b1, gate_w, (void*)h, grp);
        gemm8p<1><<<256, 512, 0, stream>>>(
            h, W2tc + (size_t)grp * TD * 2 * TH, nullptr, nullptr, d_out, grp);
    }
}

// Round 5
// 847.447 us; speedup vs baseline: 1.2194x; 1.0129x over previous
//
#include <hip/hip_runtime.h>
#include <stdint.h>

#define TD 512
#define TH 2048
#define TE 8
#define TT 16384

typedef __bf16 bf16x8 __attribute__((ext_vector_type(8)));
typedef __bf16 bf16x4 __attribute__((ext_vector_type(4)));
typedef float  f32x4  __attribute__((ext_vector_type(4)));

__device__ __forceinline__ void async16(const void* src, void* lds) {
    __builtin_amdgcn_global_load_lds((const __attribute__((address_space(1))) uint32_t*)src,
                                     (__attribute__((address_space(3))) uint32_t*)lds,
                                     16, 0, 0);
}

// ---------------------------------------------------------------------------
// Gate: per-token LayerNorm -> logits -> softmax -> gate_w; cast x->bf16;
// write out_bias[t][d] = sum_e gw[t][e]*b2[e][d] directly into d_out.
// ---------------------------------------------------------------------------
__global__ __launch_bounds__(256) void gate_kernel(
    const float* __restrict__ x, const float* __restrict__ gamma,
    const float* __restrict__ beta, const float* __restrict__ gW,
    const float* __restrict__ gb, const float* __restrict__ b2,
    float* __restrict__ gate_w, __bf16* __restrict__ xb,
    float* __restrict__ outp)
{
    const int t    = blockIdx.x * 4 + (threadIdx.x >> 6);
    const int lane = threadIdx.x & 63;

    const float* xr = x + (size_t)t * TD + lane * 8;
    float4 v0 = *(const float4*)xr;
    float4 v1 = *(const float4*)(xr + 4);
    float xv[8] = {v0.x, v0.y, v0.z, v0.w, v1.x, v1.y, v1.z, v1.w};

    float s = 0.f, sq = 0.f;
    #pragma unroll
    for (int j = 0; j < 8; ++j) { s += xv[j]; sq += xv[j] * xv[j]; }
    #pragma unroll
    for (int off = 32; off > 0; off >>= 1) {
        s  += __shfl_xor(s, off);
        sq += __shfl_xor(sq, off);
    }
    const float mean = s * (1.f / TD);
    const float var  = sq * (1.f / TD) - mean * mean;
    const float rs   = rsqrtf(var + 1e-5f);

    bf16x8 xc;
    #pragma unroll
    for (int j = 0; j < 8; ++j) xc[j] = (__bf16)xv[j];
    *(bf16x8*)&xb[(size_t)t * TD + lane * 8] = xc;

    float p[TE] = {};
    #pragma unroll
    for (int j = 0; j < 8; ++j) {
        const int d = lane * 8 + j;
        const float xn = (xv[j] - mean) * rs * gamma[d] + beta[d];
        const float* wr = gW + (size_t)d * TE;
        #pragma unroll
        for (int e = 0; e < TE; ++e) p[e] += xn * wr[e];
    }
    #pragma unroll
    for (int off = 32; off > 0; off >>= 1) {
        #pragma unroll
        for (int e = 0; e < TE; ++e) p[e] += __shfl_xor(p[e], off);
    }

    float m = -3.4e38f;
    #pragma unroll
    for (int e = 0; e < TE; ++e) { p[e] += gb[e]; m = fmaxf(m, p[e]); }
    float sum = 0.f;
    #pragma unroll
    for (int e = 0; e < TE; ++e) { p[e] = expf(p[e] - m); sum += p[e]; }
    const float inv = 1.f / sum;
    if (lane == 0) {
        #pragma unroll
        for (int e = 0; e < TE; ++e) gate_w[(size_t)t * TE + e] = p[e] * inv;
    }

    float ob[8] = {};
    #pragma unroll
    for (int e = 0; e < TE; ++e) {
        const float we = p[e] * inv;
        const float* b2r = b2 + (size_t)e * TD + lane * 8;
        #pragma unroll
        for (int j = 0; j < 8; ++j) ob[j] += we * b2r[j];
    }
    float4 o0 = {ob[0], ob[1], ob[2], ob[3]};
    float4 o1 = {ob[4], ob[5], ob[6], ob[7]};
    *(float4*)&outp[(size_t)t * TD + lane * 8]     = o0;
    *(float4*)&outp[(size_t)t * TD + lane * 8 + 4] = o1;
}

// ---------------------------------------------------------------------------
// Transpose-cast.  src f32 [E][R][C].
// MODE 0 (W1): dst[e][c][r]                      (row stride R)
// MODE 1 (W2): dst[e>>1][c][(e&1)*R + r]         (row stride 2R = 4096)
// ---------------------------------------------------------------------------
template <int MODE>
__global__ __launch_bounds__(256) void tcast(
    const float* __restrict__ src, __bf16* __restrict__ dst, int R, int C)
{
    __shared__ __bf16 tile[64][65];
    const int e  = blockIdx.z;
    const int r0 = blockIdx.y * 64, c0 = blockIdx.x * 64;
    const int tr = threadIdx.x >> 6;
    const int tc = threadIdx.x & 63;

    const float* s = src + ((size_t)e * R + r0) * C + c0;
    #pragma unroll
    for (int i = 0; i < 16; ++i) {
        const int r = i * 4 + tr;
        tile[r][tc] = (__bf16)s[(size_t)r * C + tc];
    }
    __syncthreads();

    size_t RS, eoff;
    if (MODE == 0) { RS = (size_t)R;     eoff = (size_t)e * C * R; }
    else           { RS = (size_t)2 * R; eoff = (size_t)(e >> 1) * C * 2 * R + (size_t)(e & 1) * R; }

    __bf16* d = dst + eoff + (size_t)c0 * RS + r0;
    #pragma unroll
    for (int i = 0; i < 16; ++i) {
        const int c = i * 4 + tr;
        d[(size_t)c * RS + tc] = tile[tc][c];
    }
}

// ---------------------------------------------------------------------------
// 128x256 bf16 MFMA GEMM, BK=32, 4 waves (each owns 128x64), 48 KiB LDS,
// double-buffered, 2 blocks/CU (independent-block latency hiding).
// Per iter t: vmcnt(6) [tile t landed; t==NT-1 -> vmcnt(0), tail fix] ->
//   barrier -> 12 ds_read_b128 -> lgkmcnt(0) -> barrier ->
//   stage(t+2)->buf[t&1] -> setprio(1) 32 MFMA setprio(0).
// Stage: linear LDS dest (uniform + lane*16), inverse-XOR-swizzled global
// source; read applies the same XOR (measured conflict-free in r2/r3).
//
// EPI 0 (GEMM1): A=xb [T][512], Bt=W1t, K=512 (NT=16), 2 experts/launch.
//   SWAPPED MFMA operands: lane&15 = M-row, reg j = N-col -> 8B bf16x4 store
//   h[row][e2*TH+col], row stride 2*TH.  h' = bf16(gw * leaky(acc + b1)).
// EPI 1 (GEMM2): A=h [T][4096], Bt=W2tc panel, K-half 2048/block (NT=64!),
//   kh offset 2048 elements; atomicAdd f32 into d_out.
// ---------------------------------------------------------------------------
template <int EPI>
__global__ __launch_bounds__(256, 2) void gemm2b(
    const __bf16* __restrict__ A, const __bf16* __restrict__ Bt,
    const float* __restrict__ b1, const float* __restrict__ gw,
    void* __restrict__ C, int grp)
{
    constexpr int S  = (EPI == 0) ? TD : 2 * TH;   // global row stride
    constexpr int NT = (EPI == 0) ? 16 : 64;       // K-tiles of 32 per block

    // LDS: A 2x[128][32] (2x8K) at 0, B 2x[256][32] (2x16K) at 16K
    __shared__ __align__(16) char smem[49152];

    const int tid  = threadIdx.x;
    const int w    = tid >> 6, lane = tid & 63;
    const int fr   = lane & 15, ks = lane >> 4;

    int bm, bn, e2 = 0, e = 0;
    if (EPI == 0) {
        const int xcd = blockIdx.x & 7, idx = blockIdx.x >> 3;  // 8 x 256
        bm = xcd * 16 + (idx & 15);           // 0..127
        const int pn = idx >> 4;              // 0..15
        e2 = pn >> 3;
        bn = pn & 7;
        e  = grp * 2 + e2;
        A  += (size_t)bm * 128 * S;
        Bt += (size_t)e2 * TH * TD + (size_t)bn * 256 * S;
        b1 += (size_t)e * TH;
    } else {
        const int xcd = blockIdx.x & 7, idx = blockIdx.x >> 3;  // 8 x 64
        bm = xcd * 16 + (idx & 15);           // 0..127
        const int pn = idx >> 4;              // 0..3
        const int kh = pn >> 1;               // k-half: 2048 elements each
        bn = pn & 1;
        A  += (size_t)bm * 128 * S + (size_t)kh * 2048;
        Bt += (size_t)bn * 256 * S + (size_t)kh * 2048;
    }

    const __bf16* Ab = A;
    const __bf16* Bb = Bt;

    f32x4 acc[8][4] = {};

    // stage K-tile t into buf b: A 2 passes, B 4 passes (16B per thread each)
    auto stage = [&](int t, int b) {
        char* aRegion = smem + b * 8192;
        char* bRegion = smem + 16384 + b * 16384;
        #pragma unroll
        for (int p = 0; p < 2; ++p) {
            const int cid = p * 256 + tid;
            const int row = cid >> 2;
            const int gc  = (cid & 3) ^ ((row >> 1) & 3);
            async16(Ab + (size_t)row * S + t * 32 + gc * 8, aRegion + cid * 16);
        }
        #pragma unroll
        for (int p = 0; p < 4; ++p) {
            const int cid = p * 256 + tid;
            const int row = cid >> 2;
            const int gc  = (cid & 3) ^ ((row >> 1) & 3);
            async16(Bb + (size_t)row * S + t * 32 + gc * 8, bRegion + cid * 16);
        }
    };

    stage(0, 0);
    stage(1, 1);

    for (int t = 0; t < NT; ++t) {
        const int buf = t & 1;
        const char* aR = smem + buf * 8192;
        const char* bR = smem + 16384 + buf * 16384;

        if (t + 1 < NT) { asm volatile("s_waitcnt vmcnt(6)" ::: "memory"); }
        else            { asm volatile("s_waitcnt vmcnt(0)" ::: "memory"); }  // tail: only 6 left
        __builtin_amdgcn_sched_barrier(0);
        __builtin_amdgcn_s_barrier();

        bf16x8 areg[8], breg[4];
        #pragma unroll
        for (int m = 0; m < 8; ++m) {
            const int row = m * 16 + fr;
            areg[m] = *(const bf16x8*)(aR + row * 64 + (((ks ^ (row >> 1)) & 3) << 4));
        }
        #pragma unroll
        for (int n = 0; n < 4; ++n) {
            const int row = w * 64 + n * 16 + fr;
            breg[n] = *(const bf16x8*)(bR + row * 64 + (((ks ^ (row >> 1)) & 3) << 4));
        }
        asm volatile("s_waitcnt lgkmcnt(0)" ::: "memory");
        __builtin_amdgcn_sched_barrier(0);
        __builtin_amdgcn_s_barrier();               // all waves' reads done

        if (t + 2 < NT) stage(t + 2, buf);          // overwrite just-read buf

        __builtin_amdgcn_s_setprio(1);
        #pragma unroll
        for (int m = 0; m < 8; ++m)
            #pragma unroll
            for (int n = 0; n < 4; ++n) {
                if (EPI == 0)
                    acc[m][n] = __builtin_amdgcn_mfma_f32_16x16x32_bf16(breg[n], areg[m], acc[m][n], 0, 0, 0);
                else
                    acc[m][n] = __builtin_amdgcn_mfma_f32_16x16x32_bf16(areg[m], breg[n], acc[m][n], 0, 0, 0);
            }
        __builtin_amdgcn_s_setprio(0);
        __builtin_amdgcn_sched_barrier(0);
    }

    if (EPI == 0) {
        // swapped: lane&15 = row, (lane>>4)*4 + j = col
        __bf16* hC = (__bf16*)C;
        const int rjc = (lane >> 4) << 2;
        #pragma unroll
        for (int m = 0; m < 8; ++m) {
            const int row = bm * 128 + m * 16 + fr;
            const float wgt = gw[(size_t)row * TE + e];
            __bf16* hrow = hC + (size_t)row * (2 * TH) + e2 * TH;
            #pragma unroll
            for (int n = 0; n < 4; ++n) {
                const int colb = bn * 256 + w * 64 + n * 16 + rjc;
                const f32x4 bv = *(const f32x4*)&b1[colb];
                bf16x4 ov;
                #pragma unroll
                for (int j = 0; j < 4; ++j) {
                    float v = acc[m][n][j] + bv[j];
                    v = v > 0.f ? v : 0.01f * v;
                    ov[j] = (__bf16)(v * wgt);
                }
                *(bf16x4*)&hrow[colb] = ov;
            }
        }
    } else {
        // normal: col = lane&15, row = (lane>>4)*4 + j
        float* oC = (float*)C;
        const int rj = (lane >> 4) << 2;
        #pragma unroll
        for (int m = 0; m < 8; ++m) {
            const int gr0 = bm * 128 + m * 16 + rj;
            #pragma unroll
            for (int j = 0; j < 4; ++j) {
                const int gr = gr0 + j;
                #pragma unroll
                for (int n = 0; n < 4; ++n) {
                    const int gc = bn * 256 + w * 64 + n * 16 + fr;
                    atomicAdd(oC + (size_t)gr * TD + gc, acc[m][n][j]);
                }
            }
        }
    }
}

// ---------------------------------------------------------------------------
extern "C" void kernel_launch(void* const* d_in, const int* in_sizes, int n_in,
                              void* d_out, int out_size, void* d_ws, size_t ws_size,
                              hipStream_t stream)
{
    const float* x     = (const float*)d_in[0];
    const float* gamma = (const float*)d_in[1];
    const float* beta  = (const float*)d_in[2];
    const float* gW    = (const float*)d_in[3];
    const float* gb    = (const float*)d_in[4];
    const float* W1    = (const float*)d_in[5];
    const float* b1    = (const float*)d_in[6];
    const float* W2    = (const float*)d_in[7];
    const float* b2    = (const float*)d_in[8];

    char* ws = (char*)d_ws;
    size_t off = 0;
    float*  gate_w = (float*)(ws + off);  off += (size_t)TT * TE * 4;        // 0.5 MB
    __bf16* xb     = (__bf16*)(ws + off); off += (size_t)TT * TD * 2;        // 16 MB
    __bf16* W1t    = (__bf16*)(ws + off); off += (size_t)TE * TD * TH * 2;   // 16 MB
    __bf16* W2tc   = (__bf16*)(ws + off); off += (size_t)TE * TD * TH * 2;   // 16 MB
    __bf16* h      = (__bf16*)(ws + off);                                    // 128 MB

    gate_kernel<<<TT / 4, 256, 0, stream>>>(x, gamma, beta, gW, gb, b2,
                                            gate_w, xb, (float*)d_out);
    // W1 [E][D][H] -> W1t [E][H][D]
    tcast<0><<<dim3(TH / 64, TD / 64, TE), 256, 0, stream>>>(W1, W1t, TD, TH);
    // W2 [E][H][D] -> W2tc [E/2][D][2*TH] (pair-concat along K)
    tcast<1><<<dim3(TD / 64, TH / 64, TE), 256, 0, stream>>>(W2, W2tc, TH, TD);

    for (int grp = 0; grp < 4; ++grp) {
        gemm2b<0><<<2048, 256, 0, stream>>>(
            xb, W1t + (size_t)grp * 2 * TH * TD, b1, gate_w, (void*)h, grp);
        gemm2b<1><<<512, 256, 0, stream>>>(
            h, W2tc + (size_t)grp * TD * 2 * TH, nullptr, nullptr, d_out, grp);
    }
}